// Round 17
// baseline (698.958 us; speedup 1.0000x reference)
//
#include <hip/hip_runtime.h>

// HybridGeometryFeatures via spatial grid (EXACT selection) — BISECT ROUND:
// same grid build as r16; query kernel reduced to 1 THREAD = 1 QUERY with the
// r9-proven per-thread selection machinery (sort-8 + halver + bitonic-merge-16
// on exact u64 keys). No shuffles, no LDS, no cross-lane termination.
// Index carried as (float)idx (exact, no denormals).
// Shells: after completing shell k, unprocessed points have d >= k*w; stop
// when run[15].dist < (k*w)^2 * (1-1e-4).

#define NPTS 12288
#define NBATCH 2
#define NQ (NPTS * NBATCH)
#define KNN 16
#define GD 32
#define GD3 (GD * GD * GD)
#define OFFST (GD3 + 1)
#define CLO (-6.0f)
#define CW 0.375f

typedef unsigned long long u64;
typedef unsigned int u32;

#define MIN64(a, b) ((a) < (b) ? (a) : (b))
#define SWAP64(a, b) { u64 _lo = (a) < (b) ? (a) : (b); u64 _hi = (a) < (b) ? (b) : (a); a = _lo; b = _hi; }

__device__ __forceinline__ int cellc(float v) {
  int c = (int)((v - CLO) * (1.0f / CW));
  return c < 0 ? 0 : (c > GD - 1 ? GD - 1 : c);
}

__global__ __launch_bounds__(256) void zero_kernel(u32* __restrict__ cnt) {
  int i = blockIdx.x * 256 + threadIdx.x;
  if (i < 2 * GD3) cnt[i] = 0;
}

__global__ __launch_bounds__(256) void pack_kernel(const float* __restrict__ xyz,
                                                   float4* __restrict__ pts4,
                                                   u32* __restrict__ cellid,
                                                   u32* __restrict__ cnt) {
  int i = blockIdx.x * 256 + threadIdx.x;
  if (i < NQ) {
    float x = xyz[3 * i + 0], y = xyz[3 * i + 1], z = xyz[3 * i + 2];
    pts4[i] = make_float4(x, y, z, 0.0f);
    u32 cell = (u32)((cellc(z) * GD + cellc(y)) * GD + cellc(x));
    cellid[i] = cell;
    int b = i / NPTS;
    atomicAdd(&cnt[b * GD3 + cell], 1u);
  }
}

// Exclusive scan of 32768 counts per batch (blockIdx = batch).
__global__ __launch_bounds__(1024) void scan_kernel(const u32* __restrict__ cnt,
                                                    u32* __restrict__ off,
                                                    u32* __restrict__ cur) {
  __shared__ u32 part[1024];
  int b = blockIdx.x;
  int tid = threadIdx.x;
  const u32* cb = cnt + b * GD3;
  u32* ob = off + b * OFFST;
  u32* ub = cur + b * GD3;
  u32 tmp[32];
  u32 s = 0;
#pragma unroll
  for (int i = 0; i < 32; ++i) {
    u32 c = cb[tid * 32 + i];
    tmp[i] = s;
    s += c;
  }
  part[tid] = s;
  __syncthreads();
  for (int o = 1; o < 1024; o <<= 1) {
    u32 v = (tid >= o) ? part[tid - o] : 0u;
    __syncthreads();
    part[tid] += v;
    __syncthreads();
  }
  u32 prefix = (tid == 0) ? 0u : part[tid - 1];
#pragma unroll
  for (int i = 0; i < 32; ++i) {
    u32 v = prefix + tmp[i];
    ob[tid * 32 + i] = v;
    ub[tid * 32 + i] = v;
  }
  if (tid == 1023) ob[GD3] = part[1023];
}

__global__ __launch_bounds__(256) void scatter_kernel(const float4* __restrict__ pts4,
                                                      const u32* __restrict__ cellid,
                                                      u32* __restrict__ cur,
                                                      float4* __restrict__ spts) {
  int i = blockIdx.x * 256 + threadIdx.x;
  if (i < NQ) {
    int b = i / NPTS;
    u32 cell = cellid[i];
    u32 pos = atomicAdd(&cur[b * GD3 + cell], 1u);
    float4 p = pts4[i];
    p.w = (float)(i - b * NPTS); // original local index as exact float value
    spts[b * NPTS + pos] = p;
  }
}

// ONE THREAD PER QUERY. Shell expansion; exact u64 top-16 (r9-proven network);
// per-thread termination; features inline.
__global__ __launch_bounds__(64) void query_kernel(const float4* __restrict__ pts4,
                                                   const float4* __restrict__ spts,
                                                   const u32* __restrict__ off,
                                                   const float* __restrict__ normals,
                                                   float* __restrict__ out) {
  int t = blockIdx.x * 64 + threadIdx.x; // sorted position, 0..NQ
  int b = t / NPTS;
  int j = t - b * NPTS;
  int bbase = b * NPTS;
  const float4* sp = spts + bbase;
  const u32* ob = off + b * OFFST;

  float4 Q4 = sp[j];
  float Qx = Q4.x, Qy = Q4.y, Qz = Q4.z;
  u32 qi = (u32)(int)Q4.w;
  int cqx = cellc(Qx), cqy = cellc(Qy), cqz = cellc(Qz);

  u64 run[KNN];
#pragma unroll
  for (int i = 0; i < KNN; ++i) run[i] = ~0ULL;

  auto proc8 = [&](int s, int e) {
    for (int j0 = s; j0 < e; j0 += 8) {
      u64 s0, s1, s2, s3, s4, s5, s6, s7;
#define MK(sv, M) { int jp = j0 + (M); float4 c = sp[jp < e ? jp : e - 1]; \
      float dx = Qx - c.x, dy = Qy - c.y, dz = Qz - c.z; \
      float d2 = fmaf(dz, dz, fmaf(dy, dy, dx * dx)); \
      u32 ci = (u32)(int)c.w; \
      sv = ((u64)__float_as_uint(d2) << 32) | ci; \
      if (jp >= e || ci == qi) sv = ~0ULL; }
      MK(s0, 0) MK(s1, 1) MK(s2, 2) MK(s3, 3) MK(s4, 4) MK(s5, 5) MK(s6, 6) MK(s7, 7)
#undef MK
      u64 qmin = MIN64(MIN64(MIN64(s0, s1), MIN64(s2, s3)),
                       MIN64(MIN64(s4, s5), MIN64(s6, s7)));
      if (qmin < run[15]) {
        // Batcher sort-8 ascending (r9-proven)
        SWAP64(s0, s1) SWAP64(s2, s3) SWAP64(s4, s5) SWAP64(s6, s7)
        SWAP64(s0, s2) SWAP64(s1, s3) SWAP64(s4, s6) SWAP64(s5, s7)
        SWAP64(s1, s2) SWAP64(s5, s6)
        SWAP64(s0, s4) SWAP64(s1, s5) SWAP64(s2, s6) SWAP64(s3, s7)
        SWAP64(s2, s4) SWAP64(s3, s5)
        SWAP64(s1, s2) SWAP64(s3, s4) SWAP64(s5, s6)
        // halver + bitonic-merge-16 (r9-proven)
        run[8]  = MIN64(run[8],  s7);
        run[9]  = MIN64(run[9],  s6);
        run[10] = MIN64(run[10], s5);
        run[11] = MIN64(run[11], s4);
        run[12] = MIN64(run[12], s3);
        run[13] = MIN64(run[13], s2);
        run[14] = MIN64(run[14], s1);
        run[15] = MIN64(run[15], s0);
#pragma unroll
        for (int jj = 8; jj >= 1; jj >>= 1) {
#pragma unroll
          for (int ii = 0; ii < KNN; ++ii) {
            if ((ii & jj) == 0) { SWAP64(run[ii], run[ii | jj]) }
          }
        }
      }
    }
  };

  for (int k = 0; k < GD; ++k) {
    for (int dz = -k; dz <= k; ++dz) {
      int cz = cqz + dz;
      if (cz < 0 || cz >= GD) continue;
      bool zface = (dz == -k) || (dz == k);
      for (int dy = -k; dy <= k; ++dy) {
        int cy = cqy + dy;
        if (cy < 0 || cy >= GD) continue;
        int rowbase = (cz * GD + cy) * GD;
        if (zface || dy == -k || dy == k) {
          int x0 = cqx - k; if (x0 < 0) x0 = 0;
          int x1 = cqx + k; if (x1 > GD - 1) x1 = GD - 1;
          int s = (int)ob[rowbase + x0], e = (int)ob[rowbase + x1 + 1];
          if (s < e) proc8(s, e);
        } else {
          int xa = cqx - k;
          if (xa >= 0) {
            int s = (int)ob[rowbase + xa], e = (int)ob[rowbase + xa + 1];
            if (s < e) proc8(s, e);
          }
          int xb = cqx + k;
          if (xb < GD) {
            int s = (int)ob[rowbase + xb], e = (int)ob[rowbase + xb + 1];
            if (s < e) proc8(s, e);
          }
        }
      }
    }
    // per-thread termination: unprocessed points have d >= k*w
    float d16 = __uint_as_float((u32)(run[15] >> 32)); // NaN while not full
    float kw = (float)k * CW;
    if (d16 < kw * kw * 0.9999f) break;
  }

  // ---- features (r15-proven epilogue) ----
  float nx[KNN], ny[KNN], nz[KNN];
  float sx = 0.f, sy = 0.f, sz = 0.f;
#pragma unroll
  for (int i = 0; i < KNN; ++i) {
    int ni = (int)(u32)run[i];
    float4 c4 = pts4[bbase + ni];
    nx[i] = c4.x; ny[i] = c4.y; nz[i] = c4.z;
    sx += c4.x; sy += c4.y; sz += c4.z;
  }
  const float invK = 1.0f / 16.0f;
  float cx = sx * invK, cy = sy * invK, cz = sz * invK;

  float c00 = 0.f, c01 = 0.f, c02 = 0.f, c11 = 0.f, c12 = 0.f, c22 = 0.f;
#pragma unroll
  for (int i = 0; i < KNN; ++i) {
    float dx = nx[i] - cx, dy = ny[i] - cy, dz = nz[i] - cz;
    c00 += dx * dx; c01 += dx * dy; c02 += dx * dz;
    c11 += dy * dy; c12 += dy * dz; c22 += dz * dz;
  }
  const float inv15 = 1.0f / 15.0f;
  c00 *= inv15; c01 *= inv15; c02 *= inv15;
  c11 *= inv15; c12 *= inv15; c22 *= inv15;

  double a00 = c00, a01 = c01, a02 = c02, a11 = c11, a12 = c12, a22 = c22;
  double tr = a00 + a11 + a22;
  double qm = tr * (1.0 / 3.0);
  double p1 = a01 * a01 + a02 * a02 + a12 * a12;
  double b00 = a00 - qm, b11 = a11 - qm, b22 = a22 - qm;
  double p2 = b00 * b00 + b11 * b11 + b22 * b22 + 2.0 * p1;
  double lmin = qm;
  if (p2 > 0.0) {
    double p = sqrt(p2 * (1.0 / 6.0));
    double ip = 1.0 / p;
    double q00 = b00 * ip, q01 = a01 * ip, q02 = a02 * ip;
    double q11 = b11 * ip, q12 = a12 * ip, q22 = b22 * ip;
    double det = q00 * (q11 * q22 - q12 * q12) - q01 * (q01 * q22 - q12 * q02) +
                 q02 * (q01 * q12 - q11 * q02);
    double r = 0.5 * det;
    r = r < -1.0 ? -1.0 : (r > 1.0 ? 1.0 : r);
    double phi = acos(r) * (1.0 / 3.0);
    lmin = qm + 2.0 * p * cos(phi + 2.0943951023931953);
  }

  double m00 = a00 - lmin, m11 = a11 - lmin, m22 = a22 - lmin;
  double v0x = a01 * a12 - a02 * m11;
  double v0y = a02 * a01 - m00 * a12;
  double v0z = m00 * m11 - a01 * a01;
  double v1x = a01 * m22 - a02 * a12;
  double v1y = a02 * a02 - m00 * m22;
  double v1z = m00 * a12 - a01 * a02;
  double v2x = m11 * m22 - a12 * a12;
  double v2y = a12 * a02 - a01 * m22;
  double v2z = a01 * a12 - m11 * a02;
  double n0 = v0x * v0x + v0y * v0y + v0z * v0z;
  double n1 = v1x * v1x + v1y * v1y + v1z * v1z;
  double n2 = v2x * v2x + v2y * v2y + v2z * v2z;
  double vx, vy, vz, nn;
  if (n0 >= n1 && n0 >= n2) { vx = v0x; vy = v0y; vz = v0z; nn = n0; }
  else if (n1 >= n2)        { vx = v1x; vy = v1y; vz = v1z; nn = n1; }
  else                      { vx = v2x; vy = v2y; vz = v2z; nn = n2; }
  if (nn < 1e-60) { vx = 0.0; vy = 0.0; vz = 1.0; nn = 1.0; }
  double inn = 1.0 / sqrt(nn);
  float vxf = (float)(vx * inn), vyf = (float)(vy * inn), vzf = (float)(vz * inn);

  float s = 0.f;
#pragma unroll
  for (int i = 0; i < KNN; ++i) {
    s += fabsf((nx[i] - cx) * vxf + (ny[i] - cy) * vyf + (nz[i] - cz) * vzf);
  }

  int to = bbase + (int)qi;
  float nrx = normals[3 * (size_t)to + 0];
  float nry = normals[3 * (size_t)to + 1];
  float nrz = normals[3 * (size_t)to + 2];
  float dot = vxf * nrx + vyf * nry + vzf * nrz;
  float cons = fabsf(dot);
  float trf = c00 + c11 + c22;
  float curv = (float)lmin / fmaxf(trf, 1e-8f);
  float* o = out + (size_t)to * 6;
  o[0] = cons;
  o[1] = nrx;
  o[2] = nry;
  o[3] = nrz;
  o[4] = curv;
  o[5] = s * invK;
}

extern "C" void kernel_launch(void* const* d_in, const int* in_sizes, int n_in,
                              void* d_out, int out_size, void* d_ws, size_t ws_size,
                              hipStream_t stream) {
  const float* xyz = (const float*)d_in[0];
  const float* normals = (const float*)d_in[1];
  float* out = (float*)d_out;

  float4* pts4 = (float4*)d_ws;            // NQ
  float4* spts = pts4 + NQ;                // NQ (cell-sorted, w=(float)idx)
  u32* cnt = (u32*)(spts + NQ);            // 2*GD3
  u32* cur = cnt + 2 * GD3;                // 2*GD3
  u32* off = cur + 2 * GD3;                // 2*OFFST
  u32* cellid = off + 2 * OFFST;           // NQ

  zero_kernel<<<(2 * GD3) / 256, 256, 0, stream>>>(cnt);
  pack_kernel<<<NQ / 256, 256, 0, stream>>>(xyz, pts4, cellid, cnt);
  scan_kernel<<<2, 1024, 0, stream>>>(cnt, off, cur);
  scatter_kernel<<<NQ / 256, 256, 0, stream>>>(pts4, cellid, cur, spts);
  query_kernel<<<NQ / 64, 64, 0, stream>>>(pts4, spts, off, normals, out);
}